// Round 4
// baseline (5091.102 us; speedup 1.0000x reference)
//
#include <hip/hip_runtime.h>
#include <cstdint>
#include <cstddef>

#define N_NODES 100000
#define M_EDGES 20000
#define P_PAIRS 1600000
#define CIN 768
#define HID 128
#define OUT_C 16
#define NLAYERS 16
#define LN_EPS 1e-5f

using half8  = __attribute__((ext_vector_type(8))) _Float16;
using half4v = __attribute__((ext_vector_type(4))) _Float16;
using half2v = __attribute__((ext_vector_type(2))) _Float16;
using f32x4  = __attribute__((ext_vector_type(4))) float;
using f32x2  = __attribute__((ext_vector_type(2))) float;

// fp8 (OCP e4m3) helpers: 2 channels per lane packed in a ushort
__device__ __forceinline__ f32x2 fp8x2_to_f32(unsigned short s) {
    return __builtin_amdgcn_cvt_pk_f32_fp8((int)s, false);
}
__device__ __forceinline__ unsigned short f32_to_fp8x2(float a, float b) {
    return (unsigned short)__builtin_amdgcn_cvt_pk_fp8_f32(a, b, 0, false);
}

// ------------------------- CSR build -------------------------

__global__ void hist_kernel(const int* __restrict__ v_idx, const int* __restrict__ e_idx,
                            unsigned* __restrict__ cnt_v, unsigned* __restrict__ cnt_e) {
    int p = blockIdx.x * 256 + threadIdx.x;
    if (p < P_PAIRS) {
        atomicAdd(&cnt_v[v_idx[p]], 1u);
        atomicAdd(&cnt_e[e_idx[p]], 1u);
    }
}

// ---- parallel scan: 3 phases ----
#define SCAN_EPT 16
#define SCAN_CHUNK 4096   // 256 threads * 16

__global__ void scan_block_sums(const unsigned* __restrict__ cnt, int n,
                                unsigned* __restrict__ bsum) {
    __shared__ unsigned ws[4];
    int t = threadIdx.x;
    int base = blockIdx.x * SCAN_CHUNK + t * SCAN_EPT;
    unsigned s = 0;
#pragma unroll
    for (int i = 0; i < SCAN_EPT; i++) {
        int idx = base + i;
        if (idx < n) s += cnt[idx];
    }
#pragma unroll
    for (int off = 1; off < 64; off <<= 1) s += __shfl_xor(s, off);
    int lane = t & 63, w = t >> 6;
    if (lane == 0) ws[w] = s;
    __syncthreads();
    if (t == 0) bsum[blockIdx.x] = ws[0] + ws[1] + ws[2] + ws[3];
}

__global__ void scan_tops(const unsigned* __restrict__ bsum, int B,
                          unsigned* __restrict__ bbase, unsigned* __restrict__ total_out) {
    int t = threadIdx.x;
    unsigned v = (t < B) ? bsum[t] : 0u;
    unsigned s = v;
#pragma unroll
    for (int off = 1; off < 64; off <<= 1) {
        unsigned u = __shfl_up(s, off);
        if (t >= off) s += u;
    }
    if (t < B) bbase[t] = s - v;
    if (t == 63) *total_out = s;
}

__global__ void scan_final(const unsigned* __restrict__ cnt, int n,
                           const unsigned* __restrict__ bbase,
                           unsigned* __restrict__ offs, unsigned* __restrict__ cur,
                           float* __restrict__ inv) {
    __shared__ unsigned wtot[4];
    int t = threadIdx.x;
    int lane = t & 63, w = t >> 6;
    int base = blockIdx.x * SCAN_CHUNK + t * SCAN_EPT;
    unsigned vals[SCAN_EPT];
    unsigned tsum = 0;
#pragma unroll
    for (int i = 0; i < SCAN_EPT; i++) {
        int idx = base + i;
        unsigned v = (idx < n) ? cnt[idx] : 0u;
        vals[i] = v;
        tsum += v;
    }
    unsigned s = tsum;
#pragma unroll
    for (int off = 1; off < 64; off <<= 1) {
        unsigned u = __shfl_up(s, off);
        if (lane >= off) s += u;
    }
    unsigned texcl = s - tsum;
    if (lane == 63) wtot[w] = s;
    __syncthreads();
    unsigned wbase = 0;
    for (int i = 0; i < w; i++) wbase += wtot[i];
    unsigned run = bbase[blockIdx.x] + wbase + texcl;
#pragma unroll
    for (int i = 0; i < SCAN_EPT; i++) {
        int idx = base + i;
        if (idx < n) {
            offs[idx] = run;
            cur[idx] = run;
            unsigned c = vals[i];
            inv[idx] = 1.0f / (float)(c > 1u ? c : 1u);
            run += c;
        }
    }
}

// ---- fills ----

__global__ void fill_v_kernel(const int* __restrict__ v_idx, const int* __restrict__ e_idx,
                              unsigned* __restrict__ cur_v, unsigned short* __restrict__ vert_nbr) {
    int p = blockIdx.x * 256 + threadIdx.x;
    if (p < P_PAIRS) {
        unsigned s = atomicAdd(&cur_v[v_idx[p]], 1u);
        vert_nbr[s] = (unsigned short)e_idx[p];   // e < 20000 fits u16
    }
}

__global__ void fill_e_kernel(const int* __restrict__ v_idx, const int* __restrict__ e_idx,
                              unsigned* __restrict__ cur_e, int* __restrict__ edge_nbr) {
    int p = blockIdx.x * 256 + threadIdx.x;
    if (p < P_PAIRS) {
        unsigned s = atomicAdd(&cur_e[e_idx[p]], 1u);
        edge_nbr[s] = v_idx[p];
    }
}

// ------------------------- weight transpose+convert -------------------------
// src: [K x 128] fp32 row-major (per layer), dst: [128 x K] fp16 (k-contiguous)

__global__ void convert_wT_kernel(const float* __restrict__ W, _Float16* __restrict__ WT,
                                  int K) {
    const float* src = W + (size_t)blockIdx.y * K * 128;
    _Float16* dst = WT + (size_t)blockIdx.y * K * 128;
    int idx = blockIdx.x * 256 + threadIdx.x;
    if (idx < K * 128) {
        int k = idx >> 7, n = idx & 127;
        dst[(size_t)n * K + k] = (_Float16)src[idx];
    }
}

// ------------------------- MFMA GEMM (encoder only) -------------------------

#define BK  64
#define LDK 72

__global__ __launch_bounds__(256) void mfma_gemm_kernel(
    const float* __restrict__ A, const _Float16* __restrict__ Bt,
    const float* __restrict__ bias, float* __restrict__ outp,
    int nrows, int K) {
    __shared__ _Float16 Asm[128 * LDK];
    __shared__ _Float16 Bsm[128 * LDK];
    int tid = threadIdx.x;
    int row0 = blockIdx.x * 128;
    int lane = tid & 63, wave = tid >> 6;
    int wy = wave >> 1, wx = wave & 1;
    int m16 = lane & 15, quad = lane >> 4;

    f32x4 acc[4][4];
#pragma unroll
    for (int r = 0; r < 4; r++)
#pragma unroll
        for (int c = 0; c < 4; c++) acc[r][c] = (f32x4)0.f;

    float bv[4];
#pragma unroll
    for (int c = 0; c < 4; c++) bv[c] = bias[wx * 64 + c * 16 + m16];

    for (int k0 = 0; k0 < K; k0 += BK) {
        __syncthreads();
#pragma unroll
        for (int i = 0; i < 8; i++) {
            int idx = tid + i * 256;
            int r = idx >> 4, c = idx & 15;
            int rg = row0 + r; if (rg >= nrows) rg = nrows - 1;
            float4 v = *(const float4*)(A + (size_t)rg * K + k0 + c * 4);
            half4v h = { (_Float16)v.x, (_Float16)v.y, (_Float16)v.z, (_Float16)v.w };
            *(half4v*)&Asm[r * LDK + c * 4] = h;
        }
#pragma unroll
        for (int i = 0; i < 4; i++) {
            int idx = tid + i * 256;
            int r = idx >> 3, c = idx & 7;
            half8 v = *(const half8*)(Bt + (size_t)r * K + k0 + c * 8);
            *(half8*)&Bsm[r * LDK + c * 8] = v;
        }
        __syncthreads();
#pragma unroll
        for (int ks = 0; ks < 2; ks++) {
            half8 af[4], bf[4];
#pragma unroll
            for (int r = 0; r < 4; r++)
                af[r] = *(half8*)&Asm[(wy * 64 + r * 16 + m16) * LDK + ks * 32 + quad * 8];
#pragma unroll
            for (int c = 0; c < 4; c++)
                bf[c] = *(half8*)&Bsm[(wx * 64 + c * 16 + m16) * LDK + ks * 32 + quad * 8];
#pragma unroll
            for (int r = 0; r < 4; r++)
#pragma unroll
                for (int c = 0; c < 4; c++)
                    acc[r][c] = __builtin_amdgcn_mfma_f32_16x16x32_f16(af[r], bf[c], acc[r][c], 0, 0, 0);
        }
    }
#pragma unroll
    for (int r = 0; r < 4; r++) {
#pragma unroll
        for (int v = 0; v < 4; v++) {
            int m = wy * 64 + r * 16 + quad * 4 + v;
            int row = row0 + m;
            if (row < nrows) {
#pragma unroll
                for (int c = 0; c < 4; c++) {
                    int n = wx * 64 + c * 16 + m16;
                    outp[(size_t)row * HID + n] = acc[r][c][v] + bv[c];
                }
            }
        }
    }
}

// ------------------------- LayerNorm + ReLU (layer 0) : fp32 in, fp8 out -------------------------

__global__ __launch_bounds__(256) void ln_relu_kernel(const float* __restrict__ x,
                                                      const float* __restrict__ g,
                                                      const float* __restrict__ b,
                                                      unsigned short* __restrict__ a8) {
    int row = (blockIdx.x * 256 + threadIdx.x) >> 6;
    int lane = threadIdx.x & 63;
    if (row >= N_NODES) return;
    float2 v = *(const float2*)(x + (size_t)row * HID + 2 * lane);
    float s = v.x + v.y;
#pragma unroll
    for (int off = 1; off < 64; off <<= 1) s += __shfl_xor(s, off);
    float mu = s * (1.0f / 128.0f);
    float d0 = v.x - mu, d1 = v.y - mu;
    float q = d0 * d0 + d1 * d1;
#pragma unroll
    for (int off = 1; off < 64; off <<= 1) q += __shfl_xor(q, off);
    float rstd = rsqrtf(q * (1.0f / 128.0f) + LN_EPS);
    float2 gg = *(const float2*)(g + 2 * lane);
    float2 bb = *(const float2*)(b + 2 * lane);
    float h0 = fmaxf(d0 * rstd * gg.x + bb.x, 0.f);
    float h1 = fmaxf(d1 * rstd * gg.y + bb.y, 0.f);
    a8[(size_t)row * 64 + lane] = f32_to_fp8x2(h0, h1);
}

// ------------------------- edge aggregation: Ae = em(a), fp8 in / fp8 out -------------------------

__global__ __launch_bounds__(256) void edge_agg_kernel(const unsigned short* __restrict__ a8,
                                                       const int* __restrict__ edge_nbr,
                                                       const unsigned* __restrict__ offs,
                                                       const float* __restrict__ inv_ce,
                                                       unsigned short* __restrict__ Ae8) {
    int m = blockIdx.x * 4 + (threadIdx.x >> 6);
    int lane = threadIdx.x & 63;
    unsigned beg = offs[m], end = offs[m + 1];
    float s0 = 0.f, s1 = 0.f;
    unsigned j = beg;
    for (; j + 8 <= end; j += 8) {
        int vv[8];
#pragma unroll
        for (int u = 0; u < 8; u++) vv[u] = edge_nbr[j + u];
#pragma unroll
        for (int u = 0; u < 8; u++) {
            f32x2 f = fp8x2_to_f32(a8[(size_t)vv[u] * 64 + lane]);
            s0 += f[0]; s1 += f[1];
        }
    }
    for (; j < end; j++) {
        f32x2 f = fp8x2_to_f32(a8[(size_t)edge_nbr[j] * 64 + lane]);
        s0 += f[0]; s1 += f[1];
    }
    float ic = inv_ce[m];
    Ae8[(size_t)m * 64 + lane] = f32_to_fp8x2(s0 * ic, s1 * ic);
}

// ------------------------- fused layer: z=vm(Ae); y=relu(z@W+b)*mask; x+=y; LN -> a8 -------------------------
// Valid because theta commutes with both segment-means (every edge in a vertex list
// has |e|>=1, so the bias passes through the vertex mean exactly; deg-0 rows masked).

#define ZLDK 136   // halves; LDS row stride for z/W tiles
#define YLD  132   // floats; LDS row stride for y (aliased over z/W)

__global__ __launch_bounds__(256) void layer_fused_kernel(
    const unsigned short* __restrict__ Ae8,
    const unsigned short* __restrict__ vert_nbr,
    const unsigned* __restrict__ offs, const float* __restrict__ inv_cv,
    const _Float16* __restrict__ WT,   // [128][128] fp16, k-contiguous
    const float* __restrict__ bias,
    float* __restrict__ x, const float* __restrict__ g, const float* __restrict__ b,
    unsigned short* __restrict__ a8, int do_ln) {
    __shared__ char smem[2 * 128 * ZLDK * 2];     // 69632 B: z tile + W tile, aliased by y
    __shared__ float degmask[128];
    _Float16* zsm = (_Float16*)smem;
    _Float16* wsm = zsm + 128 * ZLDK;
    float* ysm = (float*)smem;

    int tid = threadIdx.x;
    int lane = tid & 63, wave = tid >> 6;
    int m16 = lane & 15, quad = lane >> 4;
    int row0 = blockIdx.x * 128;

    // stage W tile
#pragma unroll
    for (int i = 0; i < 8; i++) {
        int idx = tid + i * 256;             // 0..2047 half8
        int r = idx >> 4, c = idx & 15;
        *(half8*)&wsm[r * ZLDK + c * 8] = *(const half8*)(WT + (size_t)r * 128 + c * 8);
    }

    // gather z = inv_cv * sum_e Ae[e]  (fp8 decode, fp32 acc, fp16 to LDS)
    for (int i = 0; i < 32; i++) {
        int rl = wave * 32 + i;
        int v = row0 + rl;
        float s0 = 0.f, s1 = 0.f, mk = 0.f;
        if (v < N_NODES) {
            unsigned beg = offs[v], end = offs[v + 1];
            if (end > beg) mk = 1.f;
            unsigned j = beg;
            for (; j + 4 <= end; j += 4) {
                int e0 = vert_nbr[j], e1 = vert_nbr[j + 1];
                int e2 = vert_nbr[j + 2], e3 = vert_nbr[j + 3];
                f32x2 f0 = fp8x2_to_f32(Ae8[(size_t)e0 * 64 + lane]);
                f32x2 f1 = fp8x2_to_f32(Ae8[(size_t)e1 * 64 + lane]);
                f32x2 f2 = fp8x2_to_f32(Ae8[(size_t)e2 * 64 + lane]);
                f32x2 f3 = fp8x2_to_f32(Ae8[(size_t)e3 * 64 + lane]);
                s0 += f0[0] + f1[0] + f2[0] + f3[0];
                s1 += f0[1] + f1[1] + f2[1] + f3[1];
            }
            for (; j < end; j++) {
                f32x2 f = fp8x2_to_f32(Ae8[(size_t)vert_nbr[j] * 64 + lane]);
                s0 += f[0]; s1 += f[1];
            }
            float ic = inv_cv[v];
            s0 *= ic; s1 *= ic;
        }
        half2v z = { (_Float16)s0, (_Float16)s1 };
        *(half2v*)&zsm[rl * ZLDK + 2 * lane] = z;
        if (lane == 0) degmask[rl] = mk;
    }
    __syncthreads();

    // MFMA: y = z @ W
    int wy = wave >> 1, wx = wave & 1;
    f32x4 acc[4][4];
#pragma unroll
    for (int r = 0; r < 4; r++)
#pragma unroll
        for (int c = 0; c < 4; c++) acc[r][c] = (f32x4)0.f;
    float bv[4];
#pragma unroll
    for (int c = 0; c < 4; c++) bv[c] = bias[wx * 64 + c * 16 + m16];
#pragma unroll
    for (int ks = 0; ks < 4; ks++) {
        half8 af[4], bf[4];
#pragma unroll
        for (int r = 0; r < 4; r++)
            af[r] = *(half8*)&zsm[(wy * 64 + r * 16 + m16) * ZLDK + ks * 32 + quad * 8];
#pragma unroll
        for (int c = 0; c < 4; c++)
            bf[c] = *(half8*)&wsm[(wx * 64 + c * 16 + m16) * ZLDK + ks * 32 + quad * 8];
#pragma unroll
        for (int r = 0; r < 4; r++)
#pragma unroll
            for (int c = 0; c < 4; c++)
                acc[r][c] = __builtin_amdgcn_mfma_f32_16x16x32_f16(af[r], bf[c], acc[r][c], 0, 0, 0);
    }
    __syncthreads();   // MFMA LDS reads done; safe to overwrite with y

    // epilogue part 1: y = relu(acc + bias) * degmask  -> LDS (C-layout scatter)
#pragma unroll
    for (int r = 0; r < 4; r++) {
#pragma unroll
        for (int vv = 0; vv < 4; vv++) {
            int rl = wy * 64 + r * 16 + quad * 4 + vv;
            float mk = degmask[rl];
#pragma unroll
            for (int c = 0; c < 4; c++) {
                int col = wx * 64 + c * 16 + m16;
                ysm[rl * YLD + col] = fmaxf(acc[r][c][vv] + bv[c], 0.f) * mk;
            }
        }
    }
    __syncthreads();

    // epilogue part 2: residual + (optional) LN -> a8
    for (int i = 0; i < 32; i++) {
        int rl = wave * 32 + i;
        int row = row0 + rl;
        if (row >= N_NODES) continue;
        float y0 = ysm[rl * YLD + 2 * lane];
        float y1 = ysm[rl * YLD + 2 * lane + 1];
        float2* xp = (float2*)(x + (size_t)row * HID + 2 * lane);
        float2 xv = *xp;
        xv.x += y0; xv.y += y1;
        *xp = xv;
        if (do_ln) {
            float s = xv.x + xv.y;
#pragma unroll
            for (int off = 1; off < 64; off <<= 1) s += __shfl_xor(s, off);
            float mu = s * (1.0f / 128.0f);
            float d0 = xv.x - mu, d1 = xv.y - mu;
            float q = d0 * d0 + d1 * d1;
#pragma unroll
            for (int off = 1; off < 64; off <<= 1) q += __shfl_xor(q, off);
            float rstd = rsqrtf(q * (1.0f / 128.0f) + LN_EPS);
            float2 gg = *(const float2*)(g + 2 * lane);
            float2 bb = *(const float2*)(b + 2 * lane);
            float h0 = fmaxf(d0 * rstd * gg.x + bb.x, 0.f);
            float h1 = fmaxf(d1 * rstd * gg.y + bb.y, 0.f);
            a8[(size_t)row * 64 + lane] = f32_to_fp8x2(h0, h1);
        }
    }
}

// ------------------------- head: x @ W_out + b_out, log_softmax -------------------------

__global__ __launch_bounds__(256) void out_kernel(const float* __restrict__ x,
                                                  const float* __restrict__ Wo,
                                                  const float* __restrict__ bo,
                                                  float* __restrict__ out) {
    __shared__ float Ws[128][16];
    __shared__ float rowbuf[16][132];
    __shared__ float bsm[16];
    int tid = threadIdx.x;
#pragma unroll
    for (int i = 0; i < 8; i++) {
        int idx = tid + i * 256;
        ((float*)Ws)[idx] = Wo[idx];
    }
    if (tid < 16) bsm[tid] = bo[tid];
    int row0 = blockIdx.x * 16;
    int w = tid >> 6, lane = tid & 63;
#pragma unroll
    for (int i = 0; i < 8; i++) {
        int idx = lane + i * 64;
        int r = idx >> 7, k = idx & 127;
        int row = row0 + w * 4 + r;
        rowbuf[w * 4 + r][k] = (row < N_NODES) ? x[(size_t)row * HID + k] : 0.f;
    }
    __syncthreads();
    int r = lane >> 4, c = lane & 15;
    int row = row0 + w * 4 + r;
    float acc = bsm[c];
#pragma unroll
    for (int k = 0; k < 128; k++) acc += rowbuf[w * 4 + r][k] * Ws[k][c];
    float mx = acc;
#pragma unroll
    for (int off = 1; off < 16; off <<= 1) mx = fmaxf(mx, __shfl_xor(mx, off));
    float e = expf(acc - mx);
    float s = e;
#pragma unroll
    for (int off = 1; off < 16; off <<= 1) s += __shfl_xor(s, off);
    float val = acc - mx - logf(s);
    if (row < N_NODES) out[(size_t)row * OUT_C + c] = val;
}

// ------------------------- launch -------------------------

extern "C" void kernel_launch(void* const* d_in, const int* in_sizes, int n_in,
                              void* d_out, int out_size, void* d_ws, size_t ws_size,
                              hipStream_t stream) {
    const float* X     = (const float*)d_in[0];
    const int*   v_idx = (const int*)d_in[1];
    const int*   e_idx = (const int*)d_in[2];
    const float* W_enc = (const float*)d_in[3];
    const float* b_enc = (const float*)d_in[4];
    const float* ln_g  = (const float*)d_in[5];
    const float* ln_b  = (const float*)d_in[6];
    const float* Wt    = (const float*)d_in[7];
    const float* bt    = (const float*)d_in[8];
    const float* W_out = (const float*)d_in[9];
    const float* b_out = (const float*)d_in[10];
    float* out = (float*)d_out;

    char* ws = (char*)d_ws;
    auto alloc = [&](size_t bytes) -> void* {
        void* p = (void*)ws;
        ws += (bytes + 255) & ~(size_t)255;
        return p;
    };
    float*          x       = (float*)alloc((size_t)N_NODES * HID * 4);
    unsigned short* a8      = (unsigned short*)alloc((size_t)N_NODES * 64 * 2);
    unsigned short* Ae8     = (unsigned short*)alloc((size_t)M_EDGES * 64 * 2);
    _Float16*       WencT_h = (_Float16*)alloc((size_t)CIN * HID * 2);
    _Float16*       WtT_h   = (_Float16*)alloc((size_t)NLAYERS * HID * HID * 2);
    int* edge_nbr = (int*)alloc((size_t)P_PAIRS * 4);
    unsigned short* vert_nbr = (unsigned short*)alloc((size_t)P_PAIRS * 2);
    unsigned* cnt_e = (unsigned*)alloc((size_t)(M_EDGES + N_NODES) * 4);
    unsigned* cnt_v = cnt_e + M_EDGES;
    unsigned* offs_e = (unsigned*)alloc((size_t)(M_EDGES + 1) * 4);
    unsigned* offs_v = (unsigned*)alloc((size_t)(N_NODES + 1) * 4);
    unsigned* cur_e  = (unsigned*)alloc((size_t)M_EDGES * 4);
    unsigned* cur_v  = (unsigned*)alloc((size_t)N_NODES * 4);
    float* inv_ce = (float*)alloc((size_t)M_EDGES * 4);
    float* inv_cv = (float*)alloc((size_t)N_NODES * 4);
    unsigned* bsum_e = (unsigned*)alloc(64 * 4);
    unsigned* bbase_e = (unsigned*)alloc(64 * 4);
    unsigned* bsum_v = (unsigned*)alloc(64 * 4);
    unsigned* bbase_v = (unsigned*)alloc(64 * 4);

    const int BE = (M_EDGES + SCAN_CHUNK - 1) / SCAN_CHUNK;   // 5
    const int BV = (N_NODES + SCAN_CHUNK - 1) / SCAN_CHUNK;   // 25

    // CSR build
    hipMemsetAsync(cnt_e, 0, (size_t)(M_EDGES + N_NODES) * 4, stream);
    hist_kernel<<<(P_PAIRS + 255) / 256, 256, 0, stream>>>(v_idx, e_idx, cnt_v, cnt_e);
    scan_block_sums<<<BE, 256, 0, stream>>>(cnt_e, M_EDGES, bsum_e);
    scan_tops<<<1, 64, 0, stream>>>(bsum_e, BE, bbase_e, offs_e + M_EDGES);
    scan_final<<<BE, 256, 0, stream>>>(cnt_e, M_EDGES, bbase_e, offs_e, cur_e, inv_ce);
    scan_block_sums<<<BV, 256, 0, stream>>>(cnt_v, N_NODES, bsum_v);
    scan_tops<<<1, 64, 0, stream>>>(bsum_v, BV, bbase_v, offs_v + N_NODES);
    scan_final<<<BV, 256, 0, stream>>>(cnt_v, N_NODES, bbase_v, offs_v, cur_v, inv_cv);
    fill_v_kernel<<<(P_PAIRS + 255) / 256, 256, 0, stream>>>(v_idx, e_idx, cur_v, vert_nbr);
    fill_e_kernel<<<(P_PAIRS + 255) / 256, 256, 0, stream>>>(v_idx, e_idx, cur_e, edge_nbr);

    // weight conversion
    {
        dim3 g1((CIN * HID + 255) / 256, 1);
        convert_wT_kernel<<<g1, 256, 0, stream>>>(W_enc, WencT_h, CIN);
        dim3 g2((HID * HID + 255) / 256, NLAYERS);
        convert_wT_kernel<<<g2, 256, 0, stream>>>(Wt, WtT_h, HID);
    }

    // encoder: x = X @ W_enc + b_enc
    mfma_gemm_kernel<<<(N_NODES + 127) / 128, 256, 0, stream>>>(
        X, WencT_h, b_enc, x, N_NODES, CIN);

    // layer-0 LN -> a8
    ln_relu_kernel<<<(N_NODES * 64 + 255) / 256, 256, 0, stream>>>(x, ln_g, ln_b, a8);

    // 16 layers: edge mean (fp8), then fused vert-mean + GEMM + residual + next LN
    for (int l = 0; l < NLAYERS; l++) {
        edge_agg_kernel<<<M_EDGES / 4, 256, 0, stream>>>(a8, edge_nbr, offs_e, inv_ce, Ae8);
        int lnext = (l + 1 < NLAYERS) ? (l + 1) : (NLAYERS - 1);
        layer_fused_kernel<<<(N_NODES + 127) / 128, 256, 0, stream>>>(
            Ae8, vert_nbr, offs_v, inv_cv,
            WtT_h + (size_t)l * HID * HID, bt + (size_t)l * HID,
            x, ln_g + (size_t)lnext * HID, ln_b + (size_t)lnext * HID, a8,
            (l + 1 < NLAYERS) ? 1 : 0);
    }

    // head
    out_kernel<<<(N_NODES + 15) / 16, 256, 0, stream>>>(x, W_out, b_out, out);
}